// Round 17
// baseline (25.078 us; speedup 1.0000x reference)
//
#include <hip/hip_runtime.h>
#include <math.h>

#define BS   8192
#define D    1024
#define NBLK 512      // block count; barrier population
#define RPB  16       // rows per block
#define F4R  4        // float4 per lane per row (D/4/64)

typedef float floatx4 __attribute__((ext_vector_type(4)));
typedef unsigned long long u64;

// ---------------------------------------------------------------------------
// Variant A: 512 threads = 8 waves/block, 2 rows/wave, A/B row pipeline.
//   1. w loads (rows A,B), w2 butterflies, block publish (epoch-tagged)
//   2. z,u loads A; wu/wz butterflies; fold vA = z + tnh*u
//   3. PER-WAVE poll (8 slots/lane, butterfly) -> wnrm; no __syncthreads
//      after this point (a barrier would vmcnt(0)-drain B's loads)
//   4. issue z,u loads B            [pinned below poll by sched_barrier]
//   5. finalize + nt-store A        -- overlaps B's loads in flight
//   6. reduce/fold/finalize/store B (vmcnt wait lands here)
// Peak liveness ~110 VGPR < 128 cap of (512,4): compiler can keep B in
// flight (R14's 256-thread attempt needed ~192 and got serialized).
// ---------------------------------------------------------------------------
__global__ __launch_bounds__(512, 4) void planar512(
    const float* __restrict__ z, const float* __restrict__ w,
    const float* __restrict__ u, const float* __restrict__ b,
    float* __restrict__ zout, float* __restrict__ ldout,
    u64* __restrict__ slots, unsigned int* __restrict__ epoch)
{
    const int t    = threadIdx.x;
    const int wv   = t >> 6;          // 0..7
    const int l    = t & 63;
    const int row0 = blockIdx.x * RPB + wv * 2;

    const unsigned int e1 =
        __hip_atomic_load(epoch, __ATOMIC_RELAXED, __HIP_MEMORY_SCOPE_AGENT)
        + 1u;

    // ---- phase 1: w loads (both rows), per-row w2, block publish ----
    float4 wr[2][F4R];
    float  w2_s[2];
    float  w2acc = 0.f;
#pragma unroll
    for (int r = 0; r < 2; ++r) {
        const float4* w4 = (const float4*)w + (size_t)(row0 + r) * (D / 4);
        float w2 = 0.f;
#pragma unroll
        for (int k = 0; k < F4R; ++k) {
            const float4 a = w4[l + (k << 6)];
            wr[r][k] = a;
            w2 += a.x*a.x + a.y*a.y + a.z*a.z + a.w*a.w;
        }
#pragma unroll
        for (int off = 32; off > 0; off >>= 1) w2 += __shfl_xor(w2, off, 64);
        w2_s[r] = w2;
        w2acc  += w2;
    }
    float brow[2];
#pragma unroll
    for (int r = 0; r < 2; ++r) brow[r] = b[row0 + r];

    __shared__ float sw[8];
    if (l == 0) sw[wv] = w2acc;
    __syncthreads();                  // only w/b loads outstanding here
    if (t == 0) {
        float p = 0.f;
#pragma unroll
        for (int i = 0; i < 8; ++i) p += sw[i];
        const u64 word = ((u64)e1 << 32) | (u64)__float_as_uint(p);
        __hip_atomic_store(&slots[blockIdx.x], word, __ATOMIC_RELAXED,
                           __HIP_MEMORY_SCOPE_AGENT);
    }

    // ---- phase 2: z,u loads row A; reduce; fold vA ----
    float4 va[F4R];
    float  wuA, inA, thA;
    {
        const float4* z4 = (const float4*)z + (size_t)row0 * (D / 4);
        const float4* u4 = (const float4*)u + (size_t)row0 * (D / 4);
        float4 zv[F4R], uv[F4R];
#pragma unroll
        for (int k = 0; k < F4R; ++k) {
            zv[k] = z4[l + (k << 6)];
            uv[k] = u4[l + (k << 6)];
        }
        float wu = 0.f, wz = 0.f;
#pragma unroll
        for (int k = 0; k < F4R; ++k) {
            const float4 a = wr[0][k];
            wu += a.x*uv[k].x + a.y*uv[k].y + a.z*uv[k].z + a.w*uv[k].w;
            wz += a.x*zv[k].x + a.y*zv[k].y + a.z*zv[k].z + a.w*zv[k].w;
        }
#pragma unroll
        for (int off = 32; off > 0; off >>= 1) {
            wu += __shfl_xor(wu, off, 64);
            wz += __shfl_xor(wz, off, 64);
        }
        inA = wz + brow[0];
        thA = tanhf(inA);
#pragma unroll
        for (int k = 0; k < F4R; ++k) {
            va[k].x = fmaf(thA, uv[k].x, zv[k].x);
            va[k].y = fmaf(thA, uv[k].y, zv[k].y);
            va[k].z = fmaf(thA, uv[k].z, zv[k].z);
            va[k].w = fmaf(thA, uv[k].w, zv[k].w);
        }
        wuA = wu;
    }

    // ---- phase 3: per-wave epoch-tag poll (no syncthreads after) ----
    u64 a[8];
    for (;;) {
        bool ok = true;
#pragma unroll
        for (int i = 0; i < 8; ++i) {
            a[i] = __hip_atomic_load(&slots[l + (i << 6)], __ATOMIC_RELAXED,
                                     __HIP_MEMORY_SCOPE_AGENT);
            ok = ok && ((unsigned int)(a[i] >> 32) == e1);
        }
        if (__all(ok)) break;
        __builtin_amdgcn_s_sleep(4);
    }
    float gs = 0.f;
#pragma unroll
    for (int i = 0; i < 8; ++i) gs += __uint_as_float((unsigned int)a[i]);
#pragma unroll
    for (int off = 32; off > 0; off >>= 1) gs += __shfl_xor(gs, off, 64);
    const float wnrm = sqrtf(gs);

    if (blockIdx.x == 0 && t == 0)
        __hip_atomic_store(epoch, e1, __ATOMIC_RELEASE,
                           __HIP_MEMORY_SCOPE_AGENT);

    __builtin_amdgcn_sched_barrier(0);   // B loads stay BELOW the poll

    // ---- phase 4: issue z,u loads row B ----
    float4 zB[F4R], uB[F4R];
    {
        const float4* z4 = (const float4*)z + (size_t)(row0 + 1) * (D / 4);
        const float4* u4 = (const float4*)u + (size_t)(row0 + 1) * (D / 4);
#pragma unroll
        for (int k = 0; k < F4R; ++k) {
            zB[k] = z4[l + (k << 6)];
            uB[k] = u4[l + (k << 6)];
        }
    }

    __builtin_amdgcn_sched_barrier(0);   // A stores stay BELOW the B issues

    // ---- phase 5: finalize + nt-store row A (overlaps B loads) ----
    {
        const float sp   = (wuA > 0.f) ? (wuA + log1pf(expf(-wuA)))
                                       : log1pf(expf(wuA));
        const float coef = (-1.f + sp - wuA) / wnrm;
        const float tc   = thA * coef;
        floatx4* o4 = (floatx4*)zout + (size_t)row0 * (D / 4);
#pragma unroll
        for (int k = 0; k < F4R; ++k) {
            floatx4 o;
            o.x = fmaf(tc, wr[0][k].x, va[k].x);
            o.y = fmaf(tc, wr[0][k].y, va[k].y);
            o.z = fmaf(tc, wr[0][k].z, va[k].z);
            o.w = fmaf(tc, wr[0][k].w, va[k].w);
            __builtin_nontemporal_store(o, o4 + l + (k << 6));
        }
        if (l == 0) {
            const float s      = fmaf(coef, w2_s[0], wuA);
            const float inner2 = fmaf(thA, s, inA);
            const float th2    = tanhf(inner2);
            const float hp     = 1.f - th2 * th2;
            ldout[row0] = logf(fabsf(fmaf(hp, s, 1.f)));
        }
    }

    // ---- phase 6: reduce + finalize + store row B ----
    {
        const int row = row0 + 1;
        float wu = 0.f, wz = 0.f;
#pragma unroll
        for (int k = 0; k < F4R; ++k) {
            const float4 aa = wr[1][k];
            wu += aa.x*uB[k].x + aa.y*uB[k].y + aa.z*uB[k].z + aa.w*uB[k].w;
            wz += aa.x*zB[k].x + aa.y*zB[k].y + aa.z*zB[k].z + aa.w*zB[k].w;
        }
#pragma unroll
        for (int off = 32; off > 0; off >>= 1) {
            wu += __shfl_xor(wu, off, 64);
            wz += __shfl_xor(wz, off, 64);
        }
        const float inner = wz + brow[1];
        const float tnh   = tanhf(inner);
        const float sp    = (wu > 0.f) ? (wu + log1pf(expf(-wu)))
                                       : log1pf(expf(wu));
        const float coef  = (-1.f + sp - wu) / wnrm;
        const float tc    = tnh * coef;
        floatx4* o4 = (floatx4*)zout + (size_t)row * (D / 4);
#pragma unroll
        for (int k = 0; k < F4R; ++k) {
            floatx4 o;
            o.x = fmaf(tc, wr[1][k].x, fmaf(tnh, uB[k].x, zB[k].x));
            o.y = fmaf(tc, wr[1][k].y, fmaf(tnh, uB[k].y, zB[k].y));
            o.z = fmaf(tc, wr[1][k].z, fmaf(tnh, uB[k].z, zB[k].z));
            o.w = fmaf(tc, wr[1][k].w, fmaf(tnh, uB[k].w, zB[k].w));
            __builtin_nontemporal_store(o, o4 + l + (k << 6));
        }
        if (l == 0) {
            const float s      = fmaf(coef, w2_s[1], wu);
            const float inner2 = fmaf(tnh, s, inner);
            const float th2    = tanhf(inner2);
            const float hp     = 1.f - th2 * th2;
            ldout[row] = logf(fabsf(fmaf(hp, s, 1.f)));
        }
    }
}

// ---------------------------------------------------------------------------
// Variant B (fallback): exact R12 kernel — 256 threads, 4 rows/wave.
// ---------------------------------------------------------------------------
__global__ __launch_bounds__(256, 2) void planar256(
    const float* __restrict__ z, const float* __restrict__ w,
    const float* __restrict__ u, const float* __restrict__ b,
    float* __restrict__ zout, float* __restrict__ ldout,
    u64* __restrict__ slots, unsigned int* __restrict__ epoch)
{
    const int t    = threadIdx.x;
    const int wv   = t >> 6;
    const int l    = t & 63;
    const int row0 = blockIdx.x * RPB + wv * 4;

    __shared__ unsigned int s_e;
    __shared__ float sw[4], sg[4];
    if (t == 0)
        s_e = __hip_atomic_load(epoch, __ATOMIC_RELAXED,
                                __HIP_MEMORY_SCOPE_AGENT);

    float4 wr[4][F4R];
    float  w2_s[4];
    float  w2acc = 0.f;
#pragma unroll
    for (int r = 0; r < 4; ++r) {
        const float4* w4 = (const float4*)w + (size_t)(row0 + r) * (D / 4);
        float w2 = 0.f;
#pragma unroll
        for (int k = 0; k < F4R; ++k) {
            const float4 a = w4[l + (k << 6)];
            wr[r][k] = a;
            w2 += a.x*a.x + a.y*a.y + a.z*a.z + a.w*a.w;
        }
#pragma unroll
        for (int off = 32; off > 0; off >>= 1) w2 += __shfl_xor(w2, off, 64);
        w2_s[r] = w2;
        w2acc  += w2;
    }
    if (l == 0) sw[wv] = w2acc;
    __syncthreads();
    const unsigned int e1 = s_e + 1u;
    if (t == 0) {
        const float p = sw[0] + sw[1] + sw[2] + sw[3];
        const u64 word = ((u64)e1 << 32) | (u64)__float_as_uint(p);
        __hip_atomic_store(&slots[blockIdx.x], word, __ATOMIC_RELAXED,
                           __HIP_MEMORY_SCOPE_AGENT);
    }

    float4 vr[4][F4R];
    float  wu_s[4], in_s[4], th_s[4];
#pragma unroll
    for (int r = 0; r < 4; ++r) {
        const int row = row0 + r;
        const float4* z4 = (const float4*)z + (size_t)row * (D / 4);
        const float4* u4 = (const float4*)u + (size_t)row * (D / 4);
        float4 zv[F4R], uv[F4R];
#pragma unroll
        for (int k = 0; k < F4R; ++k) {
            zv[k] = z4[l + (k << 6)];
            uv[k] = u4[l + (k << 6)];
        }
        float wu = 0.f, wz = 0.f;
#pragma unroll
        for (int k = 0; k < F4R; ++k) {
            const float4 a = wr[r][k];
            wu += a.x*uv[k].x + a.y*uv[k].y + a.z*uv[k].z + a.w*uv[k].w;
            wz += a.x*zv[k].x + a.y*zv[k].y + a.z*zv[k].z + a.w*zv[k].w;
        }
#pragma unroll
        for (int off = 32; off > 0; off >>= 1) {
            wu += __shfl_xor(wu, off, 64);
            wz += __shfl_xor(wz, off, 64);
        }
        const float inner = wz + b[row];
        const float tnh   = tanhf(inner);
#pragma unroll
        for (int k = 0; k < F4R; ++k) {
            vr[r][k].x = fmaf(tnh, uv[k].x, zv[k].x);
            vr[r][k].y = fmaf(tnh, uv[k].y, zv[k].y);
            vr[r][k].z = fmaf(tnh, uv[k].z, zv[k].z);
            vr[r][k].w = fmaf(tnh, uv[k].w, zv[k].w);
        }
        wu_s[r] = wu; in_s[r] = inner; th_s[r] = tnh;
    }

    u64 a0, a1;
    for (;;) {
        a0 = __hip_atomic_load(&slots[t], __ATOMIC_RELAXED,
                               __HIP_MEMORY_SCOPE_AGENT);
        a1 = __hip_atomic_load(&slots[t + 256], __ATOMIC_RELAXED,
                               __HIP_MEMORY_SCOPE_AGENT);
        if ((unsigned int)(a0 >> 32) == e1 &&
            (unsigned int)(a1 >> 32) == e1) break;
        __builtin_amdgcn_s_sleep(4);
    }
    float gs = __uint_as_float((unsigned int)a0)
             + __uint_as_float((unsigned int)a1);
#pragma unroll
    for (int off = 32; off > 0; off >>= 1) gs += __shfl_xor(gs, off, 64);
    if (l == 0) sg[wv] = gs;
    __syncthreads();
    const float wnrm = sqrtf(sg[0] + sg[1] + sg[2] + sg[3]);

    if (blockIdx.x == 0 && t == 0)
        __hip_atomic_store(epoch, e1, __ATOMIC_RELEASE,
                           __HIP_MEMORY_SCOPE_AGENT);

#pragma unroll
    for (int r = 0; r < 4; ++r) {
        const int   row  = row0 + r;
        const float wu   = wu_s[r];
        const float sp   = (wu > 0.f) ? (wu + log1pf(expf(-wu)))
                                      : log1pf(expf(wu));
        const float coef = (-1.f + sp - wu) / wnrm;
        const float tc   = th_s[r] * coef;
        floatx4* o4 = (floatx4*)zout + (size_t)row * (D / 4);
#pragma unroll
        for (int k = 0; k < F4R; ++k) {
            floatx4 o;
            o.x = fmaf(tc, wr[r][k].x, vr[r][k].x);
            o.y = fmaf(tc, wr[r][k].y, vr[r][k].y);
            o.z = fmaf(tc, wr[r][k].z, vr[r][k].z);
            o.w = fmaf(tc, wr[r][k].w, vr[r][k].w);
            __builtin_nontemporal_store(o, o4 + l + (k << 6));
        }
        if (l == 0) {
            const float s      = fmaf(coef, w2_s[r], wu);
            const float inner2 = fmaf(th_s[r], s, in_s[r]);
            const float th2    = tanhf(inner2);
            const float hp     = 1.f - th2 * th2;
            ldout[row] = logf(fabsf(fmaf(hp, s, 1.f)));
        }
    }
}

extern "C" void kernel_launch(void* const* d_in, const int* in_sizes, int n_in,
                              void* d_out, int out_size, void* d_ws, size_t ws_size,
                              hipStream_t stream) {
    const float* z = (const float*)d_in[0];
    const float* w = (const float*)d_in[1];
    const float* u = (const float*)d_in[2];
    const float* b = (const float*)d_in[3];

    float* out   = (float*)d_out;
    float* zout  = out;                    // [BS, D]
    float* ldout = out + (size_t)BS * D;   // [BS]

    u64*          slots = (u64*)d_ws;                    // [NBLK] {tag,val}
    unsigned int* epoch = (unsigned int*)(slots + NBLK); // [1]

    // Host-side occupancy gate (capture-safe, deterministic): the 512-thread
    // variant's barrier needs 2 blocks/CU co-resident.
    int nb2 = 0;
    hipError_t err =
        hipOccupancyMaxActiveBlocksPerMultiprocessor(&nb2, planar512, 512, 0);
    if (err == hipSuccess && nb2 >= 2) {
        planar512<<<NBLK, 512, 0, stream>>>(z, w, u, b, zout, ldout,
                                            slots, epoch);
    } else {
        planar256<<<NBLK, 256, 0, stream>>>(z, w, u, b, zout, ldout,
                                            slots, epoch);
    }
}